// Round 4
// baseline (2769.781 us; speedup 1.0000x reference)
//
#include <hip/hip_runtime.h>
#include <stdint.h>

// MoE: E=8 routed (top-2) + 2 shared experts, H=2048, I=5120, T=2048 tokens.
// Sparse expert compute in bf16 MFMA (16x16x32), fp32 router.
// R3: v_cvt_pk_bf16_f32 staging converts (8x fewer VALU ops) + grid swap
//     (row-tile fastest) so concurrent blocks share weight panels via L3.

#define E_ 8
#define H_ 2048
#define I_ 5120
#define T_ 2048
#define NSLOT 10           // 8 routed + 2 shared
#define LDA 36             // 32 cols + 4 pad (ushort); 72B row stride -> conflict-free b64 reads

typedef __attribute__((ext_vector_type(4))) float f32x4;
typedef __attribute__((ext_vector_type(8))) __bf16 bf16x8;
typedef __attribute__((ext_vector_type(4))) unsigned int u32x4;
typedef __attribute__((ext_vector_type(2))) unsigned int u32x2;

__device__ __forceinline__ unsigned short f2bf(float f) {
  unsigned u = __builtin_bit_cast(unsigned, f);
  u += 0x7FFFu + ((u >> 16) & 1u);   // round-to-nearest-even
  return (unsigned short)(u >> 16);
}

__device__ __forceinline__ bf16x8 ldfrag(const unsigned short* p) {
  // 8 bf16 = 16B, but row stride is 72B -> only 8B-aligned: two b64 reads
  u32x2 lo = *(const u32x2*)p;
  u32x2 hi = *(const u32x2*)(p + 4);
  u32x4 v; v[0] = lo[0]; v[1] = lo[1]; v[2] = hi[0]; v[3] = hi[1];
  return __builtin_bit_cast(bf16x8, v);
}

// 4 fp32 -> 4 bf16 via 2x v_cvt_pk_bf16_f32 (RNE), one b64 LDS write
__device__ __forceinline__ void st_bf4(unsigned short* p, f32x4 v) {
  unsigned r0, r1;
  asm("v_cvt_pk_bf16_f32 %0, %1, %2" : "=v"(r0) : "v"(v[0]), "v"(v[1]));
  asm("v_cvt_pk_bf16_f32 %0, %1, %2" : "=v"(r1) : "v"(v[2]), "v"(v[3]));
  u32x2 w; w[0] = r0; w[1] = r1;
  *(u32x2*)p = w;
}

// ---------------- router: fp32 logits, sigmoid, top-2, renormalize ----------
__global__ __launch_bounds__(64) void k_router(const float* __restrict__ x,
                                               const float* __restrict__ wr,
                                               int* __restrict__ tki,
                                               float* __restrict__ tkw) {
  const int t = blockIdx.x, lane = threadIdx.x;
  const float* xr = x + (size_t)t * H_;
  float lg[E_];
#pragma unroll
  for (int e = 0; e < E_; ++e) {
    const float* w = wr + (size_t)e * H_;
    float acc = 0.f;
    for (int k = lane; k < H_; k += 64) acc += xr[k] * w[k];
#pragma unroll
    for (int off = 32; off > 0; off >>= 1) acc += __shfl_down(acc, off);
    lg[e] = acc;  // valid on lane 0
  }
  if (lane == 0) {
    float sc[E_];
#pragma unroll
    for (int e = 0; e < E_; ++e) sc[e] = 1.f / (1.f + expf(-lg[e]));
    int b0 = 0;
#pragma unroll
    for (int e = 1; e < E_; ++e) if (sc[e] > sc[b0]) b0 = e;
    int b1 = -1;
#pragma unroll
    for (int e = 0; e < E_; ++e) {
      if (e == b0) continue;
      if (b1 < 0 || sc[e] > sc[b1]) b1 = e;
    }
    float s0 = sc[b0], s1 = sc[b1], inv = 1.f / (s0 + s1);
    tki[2 * t] = b0; tki[2 * t + 1] = b1;
    tkw[2 * t] = s0 * inv; tkw[2 * t + 1] = s1 * inv;
  }
}

// ------------- per-slot token lists (compaction), shared = identity ---------
__global__ __launch_bounds__(64) void k_lists(const int* __restrict__ tki,
                                              const float* __restrict__ tkw,
                                              int* __restrict__ elist,
                                              float* __restrict__ ew,
                                              int* __restrict__ ecnt) {
  const int s = blockIdx.x, lane = threadIdx.x;
  if (s < E_) {
    int base = 0;
    for (int c = 0; c < T_ / 64; ++c) {
      int t = c * 64 + lane;
      int i0 = tki[2 * t], i1 = tki[2 * t + 1];
      int flag = (i0 == s) ? 1 : ((i1 == s) ? 2 : 0);
      unsigned long long m = __ballot(flag != 0);
      int pre = __popcll(m & ((1ull << lane) - 1ull));
      if (flag) {
        elist[s * T_ + base + pre] = t;
        ew[s * T_ + base + pre] = tkw[2 * t + flag - 1];
      }
      base += __popcll(m);
    }
    int padded = (base + 127) & ~127;
    for (int p = base + lane; p < padded; p += 64) { elist[s * T_ + p] = 0; ew[s * T_ + p] = 0.f; }
    if (lane == 0) ecnt[s] = base;
  } else {
    for (int i = lane; i < T_; i += 64) { elist[s * T_ + i] = i; ew[s * T_ + i] = 1.f; }
    if (lane == 0) ecnt[s] = T_;
  }
}

__global__ void k_bases(const int* __restrict__ ecnt, int* __restrict__ sbase) {
  if (threadIdx.x == 0 && blockIdx.x == 0) {
    int b = 0;
    for (int s = 0; s < NSLOT; ++s) { sbase[s] = b; b += (ecnt[s] + 127) & ~127; }
  }
}

// -------- gate/up GEMM: h[r][n] = silu(x.wg^T) * (x.wu^T), bf16 out ---------
// tile 128(tok) x 64(I) x BK=32 over K=H; 4 waves (2x2); dual accumulators.
// grid: x = row-tile (fastest) so concurrent blocks share weight panels (L3).
__global__ __launch_bounds__(256) void k_gateup(
    const float* __restrict__ x,
    const float* __restrict__ wg_all, const float* __restrict__ wu_all,
    const float* __restrict__ sg_all, const float* __restrict__ su_all,
    const int* __restrict__ elist, const int* __restrict__ ecnt,
    const int* __restrict__ sbase, unsigned short* __restrict__ h) {
  const int s = blockIdx.z;
  const int cnt = ecnt[s];
  const int r0 = blockIdx.x * 128;
  if (r0 >= cnt) return;
  const int n0 = blockIdx.y * 64;
  const float* gw; const float* uw;
  if (s < E_) { gw = wg_all + (size_t)s * I_ * H_; uw = wu_all + (size_t)s * I_ * H_; }
  else        { gw = sg_all + (size_t)(s - E_) * I_ * H_; uw = su_all + (size_t)(s - E_) * I_ * H_; }
  const int* lst = elist + s * T_;
  const int hrow0 = sbase[s] + r0;

  __shared__ unsigned short sA[128 * LDA];
  __shared__ unsigned short sG[64 * LDA];
  __shared__ unsigned short sU[64 * LDA];

  const int tid = threadIdx.x;
  // A staging: 128x32 fp32, 16 floats/thread
  const int ar = tid >> 1, ac0 = (tid & 1) * 16;
  const int tok = lst[r0 + ar];
  const float* xp = x + (size_t)tok * H_ + ac0;
  // B staging: 64x32 fp32 each, 8 floats/thread
  const int br = tid >> 2, bc0 = (tid & 3) * 8;
  const float* gp = gw + (size_t)(n0 + br) * H_ + bc0;
  const float* up = uw + (size_t)(n0 + br) * H_ + bc0;

  f32x4 ra[4], rg[2], ru[2];
#pragma unroll
  for (int u = 0; u < 4; ++u) ra[u] = *(const f32x4*)(xp + u * 4);
#pragma unroll
  for (int u = 0; u < 2; ++u) { rg[u] = *(const f32x4*)(gp + u * 4); ru[u] = *(const f32x4*)(up + u * 4); }

  const int w = tid >> 6, lane = tid & 63;
  const int wr = w >> 1, wc = w & 1;
  const int fr = lane & 15, k8 = lane >> 4;

  f32x4 accg[4][2], accu[4][2];
#pragma unroll
  for (int m = 0; m < 4; ++m)
#pragma unroll
    for (int n = 0; n < 2; ++n) {
      accg[m][n] = (f32x4){0.f, 0.f, 0.f, 0.f};
      accu[m][n] = (f32x4){0.f, 0.f, 0.f, 0.f};
    }

  const int KT = H_ / 32;
  for (int kt = 0; kt < KT; ++kt) {
    __syncthreads();
#pragma unroll
    for (int u = 0; u < 4; ++u) st_bf4(sA + ar * LDA + ac0 + u * 4, ra[u]);
#pragma unroll
    for (int u = 0; u < 2; ++u) {
      st_bf4(sG + br * LDA + bc0 + u * 4, rg[u]);
      st_bf4(sU + br * LDA + bc0 + u * 4, ru[u]);
    }
    __syncthreads();
    if (kt + 1 < KT) {
      xp += 32; gp += 32; up += 32;
#pragma unroll
      for (int u = 0; u < 4; ++u) ra[u] = *(const f32x4*)(xp + u * 4);
#pragma unroll
      for (int u = 0; u < 2; ++u) { rg[u] = *(const f32x4*)(gp + u * 4); ru[u] = *(const f32x4*)(up + u * 4); }
    }
    bf16x8 af[4], gf[2], uf[2];
#pragma unroll
    for (int m = 0; m < 4; ++m) af[m] = ldfrag(sA + (wr * 64 + m * 16 + fr) * LDA + k8 * 8);
#pragma unroll
    for (int n = 0; n < 2; ++n) {
      gf[n] = ldfrag(sG + (wc * 32 + n * 16 + fr) * LDA + k8 * 8);
      uf[n] = ldfrag(sU + (wc * 32 + n * 16 + fr) * LDA + k8 * 8);
    }
#pragma unroll
    for (int m = 0; m < 4; ++m)
#pragma unroll
      for (int n = 0; n < 2; ++n) {
        accg[m][n] = __builtin_amdgcn_mfma_f32_16x16x32_bf16(af[m], gf[n], accg[m][n], 0, 0, 0);
        accu[m][n] = __builtin_amdgcn_mfma_f32_16x16x32_bf16(af[m], uf[n], accu[m][n], 0, 0, 0);
      }
  }

  // epilogue: h = silu(g)*u, bf16, masked to valid rows
#pragma unroll
  for (int m = 0; m < 4; ++m)
#pragma unroll
    for (int n = 0; n < 2; ++n)
#pragma unroll
      for (int r = 0; r < 4; ++r) {
        int rit = wr * 64 + m * 16 + k8 * 4 + r;
        if (r0 + rit < cnt) {
          float g = accg[m][n][r], uv = accu[m][n][r];
          float hv = g / (1.f + expf(-g)) * uv;
          h[(size_t)(hrow0 + rit) * I_ + (n0 + wc * 32 + n * 16 + fr)] = f2bf(hv);
        }
      }
}

// -------- down GEMM: out[tok] += w * h . wd^T (atomicAdd over slots) --------
// tile 128(tok) x 128(H) x BK=32 over K=I; 4 waves (2x2).
// grid: x = row-tile (fastest) for L3 weight-panel sharing.
__global__ __launch_bounds__(256) void k_down(
    const unsigned short* __restrict__ h,
    const float* __restrict__ wd_all, const float* __restrict__ sd_all,
    const int* __restrict__ elist, const float* __restrict__ ew,
    const int* __restrict__ ecnt, const int* __restrict__ sbase,
    float* __restrict__ out) {
  const int s = blockIdx.z;
  const int cnt = ecnt[s];
  const int r0 = blockIdx.x * 128;
  if (r0 >= cnt) return;
  const int n0 = blockIdx.y * 128;
  const float* bw = (s < E_) ? wd_all + (size_t)s * H_ * I_
                             : sd_all + (size_t)(s - E_) * H_ * I_;
  const int hrow0 = sbase[s] + r0;

  __shared__ unsigned short sA[128 * LDA];
  __shared__ unsigned short sB[128 * LDA];

  const int tid = threadIdx.x;
  // A staging: 128x32 bf16 (already bf16), 16 elems/thread
  const int ar = tid >> 1, ac0 = (tid & 1) * 16;
  const unsigned short* hp = h + (size_t)(hrow0 + ar) * I_ + ac0;
  // B staging: 128x32 fp32, 16 floats/thread
  const int brr = tid >> 1, bc0 = (tid & 1) * 16;
  const float* bp = bw + (size_t)(n0 + brr) * I_ + bc0;

  u32x4 rha[2]; f32x4 rb[4];
#pragma unroll
  for (int u = 0; u < 2; ++u) rha[u] = *(const u32x4*)(hp + u * 8);
#pragma unroll
  for (int u = 0; u < 4; ++u) rb[u] = *(const f32x4*)(bp + u * 4);

  const int w = tid >> 6, lane = tid & 63;
  const int wr = w >> 1, wc = w & 1;
  const int fr = lane & 15, k8 = lane >> 4;

  f32x4 acc[4][4];
#pragma unroll
  for (int m = 0; m < 4; ++m)
#pragma unroll
    for (int n = 0; n < 4; ++n) acc[m][n] = (f32x4){0.f, 0.f, 0.f, 0.f};

  const int KT = I_ / 32;
  for (int kt = 0; kt < KT; ++kt) {
    __syncthreads();
#pragma unroll
    for (int u = 0; u < 2; ++u) {
      u32x2 a; a[0] = rha[u][0]; a[1] = rha[u][1];
      u32x2 b; b[0] = rha[u][2]; b[1] = rha[u][3];
      *(u32x2*)(sA + ar * LDA + ac0 + u * 8) = a;
      *(u32x2*)(sA + ar * LDA + ac0 + u * 8 + 4) = b;
    }
#pragma unroll
    for (int u = 0; u < 4; ++u) st_bf4(sB + brr * LDA + bc0 + u * 4, rb[u]);
    __syncthreads();
    if (kt + 1 < KT) {
      hp += 32; bp += 32;
#pragma unroll
      for (int u = 0; u < 2; ++u) rha[u] = *(const u32x4*)(hp + u * 8);
#pragma unroll
      for (int u = 0; u < 4; ++u) rb[u] = *(const f32x4*)(bp + u * 4);
    }
    bf16x8 af[4], bf[4];
#pragma unroll
    for (int m = 0; m < 4; ++m) af[m] = ldfrag(sA + (wr * 64 + m * 16 + fr) * LDA + k8 * 8);
#pragma unroll
    for (int n = 0; n < 4; ++n) bf[n] = ldfrag(sB + (wc * 64 + n * 16 + fr) * LDA + k8 * 8);
#pragma unroll
    for (int m = 0; m < 4; ++m)
#pragma unroll
      for (int n = 0; n < 4; ++n)
        acc[m][n] = __builtin_amdgcn_mfma_f32_16x16x32_bf16(af[m], bf[n], acc[m][n], 0, 0, 0);
  }

  const int* lst = elist + s * T_;
  const float* wts = ew + s * T_;
#pragma unroll
  for (int m = 0; m < 4; ++m)
#pragma unroll
    for (int r = 0; r < 4; ++r) {
      int rit = wr * 64 + m * 16 + k8 * 4 + r;
      if (r0 + rit < cnt) {
        int t = lst[r0 + rit];
        float wgt = wts[r0 + rit];
        float* orow = out + (size_t)t * H_ + n0 + wc * 64 + fr;
#pragma unroll
        for (int n = 0; n < 4; ++n) atomicAdd(orow + n * 16, wgt * acc[m][n][r]);
      }
    }
}

extern "C" void kernel_launch(void* const* d_in, const int* in_sizes, int n_in,
                              void* d_out, int out_size, void* d_ws, size_t ws_size,
                              hipStream_t stream) {
  const float* x  = (const float*)d_in[0];
  const float* wr = (const float*)d_in[1];
  const float* wg = (const float*)d_in[2];
  const float* wu = (const float*)d_in[3];
  const float* wd = (const float*)d_in[4];
  const float* sg = (const float*)d_in[5];
  const float* su = (const float*)d_in[6];
  const float* sd = (const float*)d_in[7];
  float* out = (float*)d_out;
  char* ws = (char*)d_ws;

  // workspace layout (needs ~93.4 MB)
  int*   tki   = (int*)(ws);                 // T*2 ints
  float* tkw   = (float*)(ws + 16384);       // T*2 floats
  int*   elist = (int*)(ws + 32768);         // NSLOT*T ints
  float* ew    = (float*)(ws + 114688);      // NSLOT*T floats
  int*   ecnt  = (int*)(ws + 196608);        // NSLOT ints
  int*   sbase = (int*)(ws + 196864);        // NSLOT ints
  unsigned short* h = (unsigned short*)(ws + 262144);  // <=9216 rows x I bf16

  k_router<<<T_, 64, 0, stream>>>(x, wr, tki, tkw);
  k_lists<<<NSLOT, 64, 0, stream>>>(tki, tkw, elist, ew, ecnt);
  k_bases<<<1, 1, 0, stream>>>(ecnt, sbase);
  k_gateup<<<dim3(T_ / 128, I_ / 64, NSLOT), 256, 0, stream>>>(
      x, wg, wu, sg, su, elist, ecnt, sbase, h);
  hipMemsetAsync(out, 0, (size_t)T_ * H_ * sizeof(float), stream);
  k_down<<<dim3(T_ / 128, H_ / 128, NSLOT), 256, 0, stream>>>(
      h, wd, sd, elist, ew, ecnt, sbase, out);
}

// Round 6
// 1324.902 us; speedup vs baseline: 2.0906x; 2.0906x over previous
//
#include <hip/hip_runtime.h>
#include <stdint.h>

// MoE: E=8 routed (top-2) + 2 shared experts, H=2048, I=5120, T=2048 tokens.
// Sparse expert compute in bf16 MFMA (16x16x32), fp32 router.
// R5: revert to R2 grid order (x=n-tile fastest: panel->single-XCD affinity,
//     stride 80/16 = 0 mod 8), keep v_cvt_pk_bf16_f32 staging, BM=256 tiles
//     (512 thr / 8 waves) to halve weight panel re-fetch from HBM.

#define E_ 8
#define H_ 2048
#define I_ 5120
#define T_ 2048
#define NSLOT 10           // 8 routed + 2 shared
#define LDA 36             // 32 cols + 4 pad (ushort); 72B row stride -> conflict-free b64 reads

typedef __attribute__((ext_vector_type(4))) float f32x4;
typedef __attribute__((ext_vector_type(8))) __bf16 bf16x8;
typedef __attribute__((ext_vector_type(4))) unsigned int u32x4;
typedef __attribute__((ext_vector_type(2))) unsigned int u32x2;

__device__ __forceinline__ unsigned short f2bf(float f) {
  unsigned u = __builtin_bit_cast(unsigned, f);
  u += 0x7FFFu + ((u >> 16) & 1u);   // round-to-nearest-even
  return (unsigned short)(u >> 16);
}

__device__ __forceinline__ bf16x8 ldfrag(const unsigned short* p) {
  // 8 bf16 = 16B, but row stride is 72B -> only 8B-aligned: two b64 reads
  u32x2 lo = *(const u32x2*)p;
  u32x2 hi = *(const u32x2*)(p + 4);
  u32x4 v; v[0] = lo[0]; v[1] = lo[1]; v[2] = hi[0]; v[3] = hi[1];
  return __builtin_bit_cast(bf16x8, v);
}

// 4 fp32 -> 4 bf16 via 2x v_cvt_pk_bf16_f32 (RNE), one b64 LDS write
__device__ __forceinline__ void st_bf4(unsigned short* p, f32x4 v) {
  unsigned r0, r1;
  asm("v_cvt_pk_bf16_f32 %0, %1, %2" : "=v"(r0) : "v"(v[0]), "v"(v[1]));
  asm("v_cvt_pk_bf16_f32 %0, %1, %2" : "=v"(r1) : "v"(v[2]), "v"(v[3]));
  u32x2 w; w[0] = r0; w[1] = r1;
  *(u32x2*)p = w;
}

// ---------------- router: fp32 logits, sigmoid, top-2, renormalize ----------
__global__ __launch_bounds__(64) void k_router(const float* __restrict__ x,
                                               const float* __restrict__ wr,
                                               int* __restrict__ tki,
                                               float* __restrict__ tkw) {
  const int t = blockIdx.x, lane = threadIdx.x;
  const float* xr = x + (size_t)t * H_;
  float lg[E_];
#pragma unroll
  for (int e = 0; e < E_; ++e) {
    const float* w = wr + (size_t)e * H_;
    float acc = 0.f;
    for (int k = lane; k < H_; k += 64) acc += xr[k] * w[k];
#pragma unroll
    for (int off = 32; off > 0; off >>= 1) acc += __shfl_down(acc, off);
    lg[e] = acc;  // valid on lane 0
  }
  if (lane == 0) {
    float sc[E_];
#pragma unroll
    for (int e = 0; e < E_; ++e) sc[e] = 1.f / (1.f + expf(-lg[e]));
    int b0 = 0;
#pragma unroll
    for (int e = 1; e < E_; ++e) if (sc[e] > sc[b0]) b0 = e;
    int b1 = -1;
#pragma unroll
    for (int e = 0; e < E_; ++e) {
      if (e == b0) continue;
      if (b1 < 0 || sc[e] > sc[b1]) b1 = e;
    }
    float s0 = sc[b0], s1 = sc[b1], inv = 1.f / (s0 + s1);
    tki[2 * t] = b0; tki[2 * t + 1] = b1;
    tkw[2 * t] = s0 * inv; tkw[2 * t + 1] = s1 * inv;
  }
}

// ------------- per-slot token lists (compaction), shared = identity ---------
__global__ __launch_bounds__(64) void k_lists(const int* __restrict__ tki,
                                              const float* __restrict__ tkw,
                                              int* __restrict__ elist,
                                              float* __restrict__ ew,
                                              int* __restrict__ ecnt) {
  const int s = blockIdx.x, lane = threadIdx.x;
  if (s < E_) {
    int base = 0;
    for (int c = 0; c < T_ / 64; ++c) {
      int t = c * 64 + lane;
      int i0 = tki[2 * t], i1 = tki[2 * t + 1];
      int flag = (i0 == s) ? 1 : ((i1 == s) ? 2 : 0);
      unsigned long long m = __ballot(flag != 0);
      int pre = __popcll(m & ((1ull << lane) - 1ull));
      if (flag) {
        elist[s * T_ + base + pre] = t;
        ew[s * T_ + base + pre] = tkw[2 * t + flag - 1];
      }
      base += __popcll(m);
    }
    int padded = (base + 127) & ~127;
    for (int p = base + lane; p < padded; p += 64) { elist[s * T_ + p] = 0; ew[s * T_ + p] = 0.f; }
    if (lane == 0) ecnt[s] = base;
  } else {
    for (int i = lane; i < T_; i += 64) { elist[s * T_ + i] = i; ew[s * T_ + i] = 1.f; }
    if (lane == 0) ecnt[s] = T_;
  }
}

__global__ void k_bases(const int* __restrict__ ecnt, int* __restrict__ sbase) {
  if (threadIdx.x == 0 && blockIdx.x == 0) {
    int b = 0;
    for (int s = 0; s < NSLOT; ++s) { sbase[s] = b; b += (ecnt[s] + 127) & ~127; }
  }
}

// -------- gate/up GEMM: h[r][n] = silu(x.wg^T) * (x.wu^T), bf16 out ---------
// tile 256(tok) x 64(I) x BK=32 over K=H; 8 waves (4r x 2c); dual accums.
// grid: x = n-tile (fastest, 80 = 0 mod 8 -> panel->XCD affinity), y = row.
__global__ __launch_bounds__(512) void k_gateup(
    const float* __restrict__ x,
    const float* __restrict__ wg_all, const float* __restrict__ wu_all,
    const float* __restrict__ sg_all, const float* __restrict__ su_all,
    const int* __restrict__ elist, const int* __restrict__ ecnt,
    const int* __restrict__ sbase, unsigned short* __restrict__ h) {
  const int s = blockIdx.z;
  const int cnt = ecnt[s];
  const int r0 = blockIdx.y * 256;
  if (r0 >= cnt) return;
  const int n0 = blockIdx.x * 64;
  const float* gw; const float* uw;
  if (s < E_) { gw = wg_all + (size_t)s * I_ * H_; uw = wu_all + (size_t)s * I_ * H_; }
  else        { gw = sg_all + (size_t)(s - E_) * I_ * H_; uw = su_all + (size_t)(s - E_) * I_ * H_; }
  const int* lst = elist + s * T_;
  const int hrow0 = sbase[s] + r0;

  __shared__ unsigned short sA[256 * LDA];
  __shared__ unsigned short sG[64 * LDA];
  __shared__ unsigned short sU[64 * LDA];

  const int tid = threadIdx.x;
  // A staging: 256x32 fp32, 16 floats/thread
  const int ar = tid >> 1, ac0 = (tid & 1) * 16;
  int li = r0 + ar; if (li >= cnt) li = r0;   // clamp: rows >= cnt are masked later
  const int tok = lst[li];
  const float* xp = x + (size_t)tok * H_ + ac0;
  // B staging: 64x32 fp32 each, 4 floats/thread each
  const int br = tid >> 3, bc0 = (tid & 7) * 4;
  const float* gp = gw + (size_t)(n0 + br) * H_ + bc0;
  const float* up = uw + (size_t)(n0 + br) * H_ + bc0;

  f32x4 ra[4], rg, ru;
#pragma unroll
  for (int u = 0; u < 4; ++u) ra[u] = *(const f32x4*)(xp + u * 4);
  rg = *(const f32x4*)gp; ru = *(const f32x4*)up;

  const int w = tid >> 6, lane = tid & 63;
  const int wr = w >> 1, wc = w & 1;
  const int fr = lane & 15, k8 = lane >> 4;

  f32x4 accg[4][2], accu[4][2];
#pragma unroll
  for (int m = 0; m < 4; ++m)
#pragma unroll
    for (int n = 0; n < 2; ++n) {
      accg[m][n] = (f32x4){0.f, 0.f, 0.f, 0.f};
      accu[m][n] = (f32x4){0.f, 0.f, 0.f, 0.f};
    }

  const int KT = H_ / 32;
  for (int kt = 0; kt < KT; ++kt) {
    __syncthreads();
#pragma unroll
    for (int u = 0; u < 4; ++u) st_bf4(sA + ar * LDA + ac0 + u * 4, ra[u]);
    st_bf4(sG + br * LDA + bc0, rg);
    st_bf4(sU + br * LDA + bc0, ru);
    __syncthreads();
    if (kt + 1 < KT) {
      xp += 32; gp += 32; up += 32;
#pragma unroll
      for (int u = 0; u < 4; ++u) ra[u] = *(const f32x4*)(xp + u * 4);
      rg = *(const f32x4*)gp; ru = *(const f32x4*)up;
    }
    bf16x8 af[4], gf[2], uf[2];
#pragma unroll
    for (int m = 0; m < 4; ++m) af[m] = ldfrag(sA + (wr * 64 + m * 16 + fr) * LDA + k8 * 8);
#pragma unroll
    for (int n = 0; n < 2; ++n) {
      gf[n] = ldfrag(sG + (wc * 32 + n * 16 + fr) * LDA + k8 * 8);
      uf[n] = ldfrag(sU + (wc * 32 + n * 16 + fr) * LDA + k8 * 8);
    }
#pragma unroll
    for (int m = 0; m < 4; ++m)
#pragma unroll
      for (int n = 0; n < 2; ++n) {
        accg[m][n] = __builtin_amdgcn_mfma_f32_16x16x32_bf16(af[m], gf[n], accg[m][n], 0, 0, 0);
        accu[m][n] = __builtin_amdgcn_mfma_f32_16x16x32_bf16(af[m], uf[n], accu[m][n], 0, 0, 0);
      }
  }

  // epilogue: h = silu(g)*u, bf16, masked to valid rows
#pragma unroll
  for (int m = 0; m < 4; ++m)
#pragma unroll
    for (int n = 0; n < 2; ++n)
#pragma unroll
      for (int r = 0; r < 4; ++r) {
        int rit = wr * 64 + m * 16 + k8 * 4 + r;
        if (r0 + rit < cnt) {
          float g = accg[m][n][r], uv = accu[m][n][r];
          float hv = g / (1.f + expf(-g)) * uv;
          h[(size_t)(hrow0 + rit) * I_ + (n0 + wc * 32 + n * 16 + fr)] = f2bf(hv);
        }
      }
}

// -------- down GEMM: out[tok] += w * h . wd^T (atomicAdd over slots) --------
// tile 256(tok) x 128(H) x BK=32 over K=I; 8 waves (4r x 2c).
// grid: x = n-tile (16 = 0 mod 8 -> panel->XCD affinity), y = row.
__global__ __launch_bounds__(512) void k_down(
    const unsigned short* __restrict__ h,
    const float* __restrict__ wd_all, const float* __restrict__ sd_all,
    const int* __restrict__ elist, const float* __restrict__ ew,
    const int* __restrict__ ecnt, const int* __restrict__ sbase,
    float* __restrict__ out) {
  const int s = blockIdx.z;
  const int cnt = ecnt[s];
  const int r0 = blockIdx.y * 256;
  if (r0 >= cnt) return;
  const int n0 = blockIdx.x * 128;
  const float* bw = (s < E_) ? wd_all + (size_t)s * H_ * I_
                             : sd_all + (size_t)(s - E_) * H_ * I_;
  const int hrow0 = sbase[s] + r0;

  __shared__ unsigned short sA[256 * LDA];
  __shared__ unsigned short sB[128 * LDA];

  const int tid = threadIdx.x;
  // A staging: 256x32 bf16 (already bf16), 16 elems/thread.
  // Rows beyond cnt may read stale/garbage in-bounds h rows; outputs masked.
  const int ar = tid >> 1, ac0 = (tid & 1) * 16;
  const unsigned short* hp = h + (size_t)(hrow0 + ar) * I_ + ac0;
  // B staging: 128x32 fp32, 8 floats/thread
  const int brr = tid >> 2, bc0 = (tid & 3) * 8;
  const float* bp = bw + (size_t)(n0 + brr) * I_ + bc0;

  u32x4 rha[2]; f32x4 rb[2];
#pragma unroll
  for (int u = 0; u < 2; ++u) rha[u] = *(const u32x4*)(hp + u * 8);
#pragma unroll
  for (int u = 0; u < 2; ++u) rb[u] = *(const f32x4*)(bp + u * 4);

  const int w = tid >> 6, lane = tid & 63;
  const int wr = w >> 1, wc = w & 1;
  const int fr = lane & 15, k8 = lane >> 4;

  f32x4 acc[4][4];
#pragma unroll
  for (int m = 0; m < 4; ++m)
#pragma unroll
    for (int n = 0; n < 4; ++n) acc[m][n] = (f32x4){0.f, 0.f, 0.f, 0.f};

  const int KT = I_ / 32;
  for (int kt = 0; kt < KT; ++kt) {
    __syncthreads();
#pragma unroll
    for (int u = 0; u < 2; ++u) {
      u32x2 a; a[0] = rha[u][0]; a[1] = rha[u][1];
      u32x2 b; b[0] = rha[u][2]; b[1] = rha[u][3];
      *(u32x2*)(sA + ar * LDA + ac0 + u * 8) = a;
      *(u32x2*)(sA + ar * LDA + ac0 + u * 8 + 4) = b;
    }
#pragma unroll
    for (int u = 0; u < 2; ++u) st_bf4(sB + brr * LDA + bc0 + u * 4, rb[u]);
    __syncthreads();
    if (kt + 1 < KT) {
      hp += 32; bp += 32;
#pragma unroll
      for (int u = 0; u < 2; ++u) rha[u] = *(const u32x4*)(hp + u * 8);
#pragma unroll
      for (int u = 0; u < 2; ++u) rb[u] = *(const f32x4*)(bp + u * 4);
    }
    bf16x8 af[4], bf[4];
#pragma unroll
    for (int m = 0; m < 4; ++m) af[m] = ldfrag(sA + (wr * 64 + m * 16 + fr) * LDA + k8 * 8);
#pragma unroll
    for (int n = 0; n < 4; ++n) bf[n] = ldfrag(sB + (wc * 64 + n * 16 + fr) * LDA + k8 * 8);
#pragma unroll
    for (int m = 0; m < 4; ++m)
#pragma unroll
      for (int n = 0; n < 4; ++n)
        acc[m][n] = __builtin_amdgcn_mfma_f32_16x16x32_bf16(af[m], bf[n], acc[m][n], 0, 0, 0);
  }

  const int* lst = elist + s * T_;
  const float* wts = ew + s * T_;
#pragma unroll
  for (int m = 0; m < 4; ++m)
#pragma unroll
    for (int r = 0; r < 4; ++r) {
      int rit = wr * 64 + m * 16 + k8 * 4 + r;
      if (r0 + rit < cnt) {
        int t = lst[r0 + rit];
        float wgt = wts[r0 + rit];
        float* orow = out + (size_t)t * H_ + n0 + wc * 64 + fr;
#pragma unroll
        for (int n = 0; n < 4; ++n) atomicAdd(orow + n * 16, wgt * acc[m][n][r]);
      }
    }
}

extern "C" void kernel_launch(void* const* d_in, const int* in_sizes, int n_in,
                              void* d_out, int out_size, void* d_ws, size_t ws_size,
                              hipStream_t stream) {
  const float* x  = (const float*)d_in[0];
  const float* wr = (const float*)d_in[1];
  const float* wg = (const float*)d_in[2];
  const float* wu = (const float*)d_in[3];
  const float* wd = (const float*)d_in[4];
  const float* sg = (const float*)d_in[5];
  const float* su = (const float*)d_in[6];
  const float* sd = (const float*)d_in[7];
  float* out = (float*)d_out;
  char* ws = (char*)d_ws;

  // workspace layout (needs ~94.7 MB)
  int*   tki   = (int*)(ws);                 // T*2 ints
  float* tkw   = (float*)(ws + 16384);       // T*2 floats
  int*   elist = (int*)(ws + 32768);         // NSLOT*T ints
  float* ew    = (float*)(ws + 114688);      // NSLOT*T floats
  int*   ecnt  = (int*)(ws + 196608);        // NSLOT ints
  int*   sbase = (int*)(ws + 196864);        // NSLOT ints
  unsigned short* h = (unsigned short*)(ws + 262144);  // <=9216 rows x I bf16

  k_router<<<T_, 64, 0, stream>>>(x, wr, tki, tkw);
  k_lists<<<NSLOT, 64, 0, stream>>>(tki, tkw, elist, ew, ecnt);
  k_bases<<<1, 1, 0, stream>>>(ecnt, sbase);
  k_gateup<<<dim3(I_ / 64, T_ / 256, NSLOT), 512, 0, stream>>>(
      x, wg, wu, sg, su, elist, ecnt, sbase, h);
  hipMemsetAsync(out, 0, (size_t)T_ * H_ * sizeof(float), stream);
  k_down<<<dim3(H_ / 128, T_ / 256, NSLOT), 512, 0, stream>>>(
      h, wd, sd, elist, ew, ecnt, sbase, out);
}